// Round 13
// baseline (111.208 us; speedup 1.0000x reference)
//
#include <hip/hip_runtime.h>
#include <stdint.h>

#define B_   16
#define CIN  4
#define COUT 8
#define H_   512
#define W_   512
#define HP   (H_ + 2)
#define WP   (W_ + 2)
#define PMAX 756
#define RPB  8                    // output rows per block
#define GY   (H_ / RPB)           // 64
#define NBLK (2 * GY * B_)        // 2048 blocks
#define NQ   (B_ * HP)            // 8224 quant blocks (div by 8)

__device__ __forceinline__ int dot4(uint32_t a, int b, int c) {
#if __has_builtin(__builtin_amdgcn_sdot4)
    return __builtin_amdgcn_sdot4((int)a, b, c, false);
#else
    int r = c;
#pragma unroll
    for (int i = 0; i < 4; ++i) {
        int av = (int)((a >> (8 * i)) & 0xFFu);
        int bv = ((int)(((uint32_t)b) << (24 - 8 * i))) >> 24;
        r += av * bv;
    }
    return r;
#endif
}

__device__ __forceinline__ int dot8(uint32_t a, int b, int c) {
#if __has_builtin(__builtin_amdgcn_sdot8)
    return __builtin_amdgcn_sdot8((int)a, b, c, false);
#else
    int r = c;
#pragma unroll
    for (int i = 0; i < 8; ++i) {
        int av = (int)((a >> (4 * i)) & 0xFu);
        int bv = ((int)(((uint32_t)b) << (28 - 4 * i))) >> 28;
        r += av * bv;
    }
    return r;
#endif
}

__device__ __forceinline__ float rfl_f(float v) {
    return __int_as_float(__builtin_amdgcn_readfirstlane(__float_as_int(v)));
}

// Newton-corrected reciprocal (hoisted once per divisor).
__device__ __forceinline__ float recip1(float d) {
    float y0 = __builtin_amdgcn_rcpf(d);
    float e  = fmaf(-d, y0, 1.0f);
    return fmaf(y0, e, y0);
}
// Markstein correctly-rounded division n/d given y=recip1(d).
// Field-validated bit-exact vs __fdiv_rn in round 12 (absmax=0 on 134M outputs).
__device__ __forceinline__ float mdiv(float n, float d, float y) {
    float q0 = __fmul_rn(n, y);
    float rr = fmaf(-d, q0, n);
    return fmaf(rr, y, q0);
}

// ADC of one integer psum: fl( clip(rint(p/step), +-127) * step )
__device__ __forceinline__ float adc1(int a, float step, float istep) {
    float pf = (float)a;                      // exact, |a| <= 756
    float q  = rintf(mdiv(pf, step, istep));
    q = fminf(fmaxf(q, -127.0f), 127.0f);
    return __fmul_rn(q, step);
}

__device__ __forceinline__ int wquant(const float* w, float s_w,
                                      int co, int ci, int tap) {
    const int kh = tap / 3, kw = tap % 3;
    float wv = w[((co * CIN + ci) * 3 + kh) * 3 + kw];
    float q  = rintf(__fdiv_rn(wv, s_w));
    q = fminf(fmaxf(q, -7.0f), 7.0f);
    return (int)q;
}

// ---------------- quant + weight pack ----------------
__global__ __launch_bounds__(128) void quant_pack_kernel(
        const float* __restrict__ x, const float* __restrict__ weight,
        const float* __restrict__ s_in_p, const float* __restrict__ s_w_p,
        uint32_t* __restrict__ xq, uint32_t* __restrict__ wq8) {
    const int raw = blockIdx.x;
    const int lin = (raw & 7) * (NQ / 8) + (raw >> 3);
    const int b = lin / HP, hp = lin % HP;
    const int t = threadIdx.x;
    if (raw == 0) {
        const float s_w = *s_w_p;
        if (t < 32) {                        // nibble pairs (0,1)(3,4)(6,7)(2,5)
            const int co = t >> 2, p = t & 3;
            const int tA = (p == 0) ? 0 : (p == 1) ? 3 : (p == 2) ? 6 : 2;
            const int tB = (p == 0) ? 1 : (p == 1) ? 4 : (p == 2) ? 7 : 5;
            uint32_t v = 0;
#pragma unroll
            for (int ci = 0; ci < CIN; ++ci) {
                v |= ((uint32_t)(wquant(weight, s_w, co, ci, tA) & 0xF)) << (8 * ci);
                v |= ((uint32_t)(wquant(weight, s_w, co, ci, tB) & 0xF)) << (8 * ci + 4);
            }
            wq8[t] = v;
        } else if (t < 40) {                 // tap-8 bytes
            const int co = t - 32;
            uint32_t v = 0;
#pragma unroll
            for (int ci = 0; ci < CIN; ++ci)
                v |= ((uint32_t)(wquant(weight, s_w, co, ci, 8) & 0xFF)) << (8 * ci);
            wq8[32 + co] = v;
        }
    }
    uint32_t* dst = xq + ((size_t)b * HP + hp) * WP;
    if (hp == 0 || hp == HP - 1) {
        for (int i = t; i < WP; i += 128) dst[i] = 0;
        return;
    }
    const float s_in = *s_in_p;
    const float yin  = recip1(s_in);
    const int h = hp - 1;
    const size_t plane = (size_t)H_ * W_;
    const float* xr = x + ((size_t)b * CIN) * plane + (size_t)h * W_ + 4 * t;
    float4 v0 = *(const float4*)(xr);
    float4 v1 = *(const float4*)(xr + plane);
    float4 v2 = *(const float4*)(xr + 2 * plane);
    float4 v3 = *(const float4*)(xr + 3 * plane);
    uint32_t o0 = 0, o1 = 0, o2 = 0, o3 = 0;
#define QP(f, ci, oj)                                                  \
    { float q = rintf(mdiv((f), s_in, yin));                           \
      q = fminf(fmaxf(q, 0.0f), 255.0f);                               \
      oj |= ((uint32_t)(int)q) << (8 * (ci)); }
    QP(v0.x, 0, o0) QP(v0.y, 0, o1) QP(v0.z, 0, o2) QP(v0.w, 0, o3)
    QP(v1.x, 1, o0) QP(v1.y, 1, o1) QP(v1.z, 1, o2) QP(v1.w, 1, o3)
    QP(v2.x, 2, o0) QP(v2.y, 2, o1) QP(v2.z, 2, o2) QP(v2.w, 2, o3)
    QP(v3.x, 3, o0) QP(v3.y, 3, o1) QP(v3.z, 3, o2) QP(v3.w, 3, o3)
#undef QP
    uint32_t* d = dst + 1 + 4 * t;
    d[0] = o0; d[1] = o1; d[2] = o2; d[3] = o3;
    if (t == 0) dst[0] = 0;
    if (t == 127) dst[WP - 1] = 0;
}

// ---------------- shared conv machinery ----------------
#define LOADW()                                                              \
    int w8s[32], w4s[8];                                                     \
    {                                                                        \
        const int4* q4 = (const int4*)wq8;                                   \
        _Pragma("unroll")                                                    \
        for (int i = 0; i < 8; ++i) {                                        \
            int4 w4i = q4[i];                                                \
            w8s[4 * i + 0] = __builtin_amdgcn_readfirstlane(w4i.x);          \
            w8s[4 * i + 1] = __builtin_amdgcn_readfirstlane(w4i.y);          \
            w8s[4 * i + 2] = __builtin_amdgcn_readfirstlane(w4i.z);          \
            w8s[4 * i + 3] = __builtin_amdgcn_readfirstlane(w4i.w);          \
        }                                                                    \
        int4 a0 = q4[8], a1 = q4[9];                                         \
        w4s[0] = __builtin_amdgcn_readfirstlane(a0.x);                       \
        w4s[1] = __builtin_amdgcn_readfirstlane(a0.y);                       \
        w4s[2] = __builtin_amdgcn_readfirstlane(a0.z);                       \
        w4s[3] = __builtin_amdgcn_readfirstlane(a0.w);                       \
        w4s[4] = __builtin_amdgcn_readfirstlane(a1.x);                       \
        w4s[5] = __builtin_amdgcn_readfirstlane(a1.y);                       \
        w4s[6] = __builtin_amdgcn_readfirstlane(a1.z);                       \
        w4s[7] = __builtin_amdgcn_readfirstlane(a1.w);                       \
    }

#define SWZ()                                                                \
    const int raw = blockIdx.x;                                              \
    const int lin = (raw & 7) * (NBLK / 8) + (raw >> 3);                     \
    const int bx = lin & 1;                                                  \
    const int hy = (lin >> 1) & (GY - 1);                                    \
    const int b  = lin >> 7;                                                 \
    const int w0 = bx * 256 + threadIdx.x;                                   \
    const int h0 = hy * RPB;

#define EXTS(CA, SG, v0, v1, v2)                                             \
    do {                                                                     \
        uint32_t lo_ = ((v0) & 0x0F0F0F0Fu) | (((v1) << 4) & 0xF0F0F0F0u);   \
        uint32_t hi_ = (((v0) >> 4) & 0x0F0F0F0Fu) | ((v1) & 0xF0F0F0F0u);   \
        CA[0] = lo_ & 0x33333333u;                                           \
        CA[1] = (lo_ >> 2) & 0x33333333u;                                    \
        CA[2] = hi_ & 0x33333333u;                                           \
        CA[3] = (hi_ >> 2) & 0x33333333u;                                    \
        SG[0] = (v2)&0x03030303u;                                            \
        SG[1] = ((v2) >> 2) & 0x03030303u;                                   \
        SG[2] = ((v2) >> 4) & 0x03030303u;                                   \
        SG[3] = ((v2) >> 6) & 0x03030303u;                                   \
    } while (0)

#define RING_INIT()                                                          \
    uint32_t cA0[4], cA1[4], cA2[4], cA3[4];                                 \
    uint32_t sg0[4], sg1[4], sg2[4], sg3[4];                                 \
    {                                                                        \
        uint32_t r0 = base[0], r1 = base[1], r2 = base[2];                   \
        EXTS(cA0, sg0, r0, r1, r2);                                          \
        r0 = base[WP]; r1 = base[WP + 1]; r2 = base[WP + 2];                 \
        EXTS(cA1, sg1, r0, r1, r2);                                          \
    }                                                                        \
    uint32_t n0 = base[2 * WP], n1 = base[2 * WP + 1], n2 = base[2 * WP + 2];

#define PREF(S)                                                              \
    if ((S) < RPB - 1) {                                                     \
        const uint32_t* nr_ = base + (size_t)((S) + 3) * WP;                 \
        n0 = nr_[0]; n1 = nr_[1]; n2 = nr_[2];                               \
    }

#define DOTS(CAa, SGa, CAb, SGb, CAc, SGc, K, OUTV)                          \
    {                                                                        \
        int a_ = dot4(SGc[K], w4s[co], 0);                                   \
        a_ = dot8(CAa[K], w8s[co * 4 + 0], a_);                              \
        a_ = dot8(CAb[K], w8s[co * 4 + 1], a_);                              \
        a_ = dot8(CAc[K], w8s[co * 4 + 2], a_);                              \
        a_ = dot8(K == 0 ? pc0 : K == 1 ? pc1 : K == 2 ? pc2 : pc3,          \
                  w8s[co * 4 + 3], a_);                                      \
        OUTV = a_;                                                           \
    }

// ---------------- pass 1: absmax ----------------
#define STEP1(S, CAa, SGa, CAb, SGb, CAc, SGc)                               \
    do {                                                                     \
        EXTS(CAc, SGc, n0, n1, n2);                                          \
        PREF(S);                                                             \
        const uint32_t pc0 = SGa[0] | (SGb[0] << 4);                         \
        const uint32_t pc1 = SGa[1] | (SGb[1] << 4);                         \
        const uint32_t pc2 = SGa[2] | (SGb[2] << 4);                         \
        const uint32_t pc3 = SGa[3] | (SGb[3] << 4);                         \
        _Pragma("unroll")                                                    \
        for (int co = 0; co < COUT; ++co) {                                  \
            int a0, a1, a2, a3;                                              \
            DOTS(CAa, SGa, CAb, SGb, CAc, SGc, 0, a0);                       \
            DOTS(CAa, SGa, CAb, SGb, CAc, SGc, 1, a1);                       \
            DOTS(CAa, SGa, CAb, SGb, CAc, SGc, 2, a2);                       \
            DOTS(CAa, SGa, CAb, SGb, CAc, SGc, 3, a3);                       \
            rMax0 = max(rMax0, a0); rMin0 = min(rMin0, a0);                  \
            rMax1 = max(rMax1, a1); rMin1 = min(rMin1, a1);                  \
            rMax2 = max(rMax2, a2); rMin2 = min(rMin2, a2);                  \
            rMax3 = max(rMax3, a3); rMin3 = min(rMin3, a3);                  \
        }                                                                    \
    } while (0)

__global__ __launch_bounds__(256, 8) void conv_absmax(
        const uint32_t* __restrict__ xq, const uint32_t* __restrict__ wq8,
        int* __restrict__ blkmax) {
    __shared__ int red[4];
    LOADW();
    SWZ();
    const uint32_t* base = xq + ((size_t)b * HP + h0) * WP + w0;
    RING_INIT();
    int rMax0 = 0, rMax1 = 0, rMax2 = 0, rMax3 = 0;
    int rMin0 = 0, rMin1 = 0, rMin2 = 0, rMin3 = 0;
    STEP1(0, cA0, sg0, cA1, sg1, cA2, sg2);
    STEP1(1, cA1, sg1, cA2, sg2, cA3, sg3);
    STEP1(2, cA2, sg2, cA3, sg3, cA0, sg0);
    STEP1(3, cA3, sg3, cA0, sg0, cA1, sg1);
    STEP1(4, cA0, sg0, cA1, sg1, cA2, sg2);
    STEP1(5, cA1, sg1, cA2, sg2, cA3, sg3);
    STEP1(6, cA2, sg2, cA3, sg3, cA0, sg0);
    STEP1(7, cA3, sg3, cA0, sg0, cA1, sg1);
    int m = max(max(max(rMax0, -rMin0), max(rMax1, -rMin1)),
                max(max(rMax2, -rMin2), max(rMax3, -rMin3)));
#pragma unroll
    for (int off = 1; off < 64; off <<= 1)
        m = max(m, __shfl_xor(m, off));
    if ((threadIdx.x & 63) == 0) red[threadIdx.x >> 6] = m;
    __syncthreads();
    if (threadIdx.x == 0)
        blkmax[raw] = max(max(red[0], red[1]), max(red[2], red[3]));
}

__global__ __launch_bounds__(256) void reduce_absmax(
        const int* __restrict__ blkmax, int* __restrict__ absmax) {
    __shared__ int red[4];
    const int t = threadIdx.x;
    int m = 0;
#pragma unroll
    for (int i = 0; i < NBLK / 256; ++i) m = max(m, blkmax[t + 256 * i]);
#pragma unroll
    for (int off = 1; off < 64; off <<= 1)
        m = max(m, __shfl_xor(m, off));
    if ((t & 63) == 0) red[t >> 6] = m;
    __syncthreads();
    if (t == 0)
        *absmax = max(max(red[0], red[1]), max(red[2], red[3]));
}

// ---------------- pass 2: LUT-free ALU ADC ----------------
#define STEP2(S, CAa, SGa, CAb, SGb, CAc, SGc)                               \
    do {                                                                     \
        EXTS(CAc, SGc, n0, n1, n2);                                          \
        PREF(S);                                                             \
        const uint32_t pc0 = SGa[0] | (SGb[0] << 4);                         \
        const uint32_t pc1 = SGa[1] | (SGb[1] << 4);                         \
        const uint32_t pc2 = SGa[2] | (SGb[2] << 4);                         \
        const uint32_t pc3 = SGa[3] | (SGb[3] << 4);                         \
        float* orow = out + ((size_t)b * COUT * H_ + (size_t)(h0 + (S))) * W_ + w0; \
        _Pragma("unroll")                                                    \
        for (int co = 0; co < COUT; ++co) {                                  \
            int a0, a1, a2, a3;                                              \
            DOTS(CAa, SGa, CAb, SGb, CAc, SGc, 0, a0);                       \
            DOTS(CAa, SGa, CAb, SGb, CAc, SGc, 1, a1);                       \
            DOTS(CAa, SGa, CAb, SGb, CAc, SGc, 2, a2);                       \
            DOTS(CAa, SGa, CAb, SGb, CAc, SGc, 3, a3);                       \
            float t0 = adc1(a0, step, istep);                                \
            float t1 = adc1(a1, step, istep);                                \
            float t2 = adc1(a2, step, istep);                                \
            float t3 = adc1(a3, step, istep);                                \
            float of = __fadd_rn(t0, __fmul_rn(t1, 4.0f));                   \
            of = __fadd_rn(of, __fmul_rn(t2, 16.0f));                       \
            of = __fadd_rn(of, __fmul_rn(t3, 64.0f));                       \
            float o_ = __fadd_rn(__fmul_rn(of, scale), br[co]);              \
            float q_ = rintf(mdiv(o_, s_out, y1));                          \
            q_ = fminf(fmaxf(q_, -127.0f), 127.0f);                          \
            orow[(size_t)co * plane] = __fmul_rn(q_, s_out);                 \
        }                                                                    \
    } while (0)

__global__ __launch_bounds__(256) void conv_out(
        const uint32_t* __restrict__ xq, const uint32_t* __restrict__ wq8,
        const float* __restrict__ bias, const float* __restrict__ sp_in,
        const float* __restrict__ sp_w, const float* __restrict__ sp_out,
        const int* __restrict__ absmax, float* __restrict__ out) {
    LOADW();
    const float pabs = fmaxf((float)(*absmax), 1e-6f);
    const float c63  = 1.0f / 63.0f;
    float g = rintf(__fdiv_rn(127.0f, __fmul_rn(pabs, c63)));
    g = fminf(fmaxf(g, 1.0f), 255.0f);
    const float step  = __fdiv_rn(1.0f, __fmul_rn(g, c63));
    const float istep = recip1(step);
    const float scale = __fmul_rn(rfl_f(*sp_in), rfl_f(*sp_w));
    const float s_out = rfl_f(*sp_out);
    const float y1    = recip1(s_out);
    float br[COUT];
#pragma unroll
    for (int co = 0; co < COUT; ++co) br[co] = rfl_f(bias[co]);

    SWZ();
    const uint32_t* base = xq + ((size_t)b * HP + h0) * WP + w0;
    const size_t plane = (size_t)H_ * W_;
    RING_INIT();
    STEP2(0, cA0, sg0, cA1, sg1, cA2, sg2);
    STEP2(1, cA1, sg1, cA2, sg2, cA3, sg3);
    STEP2(2, cA2, sg2, cA3, sg3, cA0, sg0);
    STEP2(3, cA3, sg3, cA0, sg0, cA1, sg1);
    STEP2(4, cA0, sg0, cA1, sg1, cA2, sg2);
    STEP2(5, cA1, sg1, cA2, sg2, cA3, sg3);
    STEP2(6, cA2, sg2, cA3, sg3, cA0, sg0);
    STEP2(7, cA3, sg3, cA0, sg0, cA1, sg1);
}

extern "C" void kernel_launch(void* const* d_in, const int* in_sizes, int n_in,
                              void* d_out, int out_size, void* d_ws, size_t ws_size,
                              hipStream_t stream) {
    const float* x      = (const float*)d_in[0];
    const float* weight = (const float*)d_in[1];
    const float* bias   = (const float*)d_in[2];
    const float* s_in   = (const float*)d_in[3];
    const float* s_w    = (const float*)d_in[4];
    const float* s_out  = (const float*)d_in[5];
    float* out = (float*)d_out;

    int*      absmax = (int*)d_ws;
    uint32_t* wq8    = (uint32_t*)((char*)d_ws + 256);    // 40 u32
    int*      blkmax = (int*)((char*)d_ws + 1024);        // 2048 ints
    uint32_t* xq     = (uint32_t*)((char*)d_ws + 16384);

    quant_pack_kernel<<<dim3(NQ), dim3(128), 0, stream>>>(
        x, weight, s_in, s_w, xq, wq8);

    conv_absmax<<<dim3(NBLK), dim3(256), 0, stream>>>(xq, wq8, blkmax);

    reduce_absmax<<<dim3(1), dim3(256), 0, stream>>>(blkmax, absmax);

    conv_out<<<dim3(NBLK), dim3(256), 0, stream>>>(
        xq, wq8, bias, s_in, s_w, s_out, absmax, out);
}

// Round 14
// 104.654 us; speedup vs baseline: 1.0626x; 1.0626x over previous
//
#include <hip/hip_runtime.h>
#include <stdint.h>

#define B_   16
#define CIN  4
#define COUT 8
#define H_   512
#define W_   512
#define HP   (H_ + 2)
#define WP   (W_ + 2)
#define PMAX 756
#define TBL  (2 * PMAX + 1)
#define RPB  8                    // output rows per block
#define GY   (H_ / RPB)           // 64
#define NBLK (2 * GY * B_)        // 2048 blocks

__device__ __forceinline__ int dot4(uint32_t a, int b, int c) {
#if __has_builtin(__builtin_amdgcn_sdot4)
    return __builtin_amdgcn_sdot4((int)a, b, c, false);
#else
    int r = c;
#pragma unroll
    for (int i = 0; i < 4; ++i) {
        int av = (int)((a >> (8 * i)) & 0xFFu);
        int bv = ((int)(((uint32_t)b) << (24 - 8 * i))) >> 24;
        r += av * bv;
    }
    return r;
#endif
}

__device__ __forceinline__ int dot8(uint32_t a, int b, int c) {
#if __has_builtin(__builtin_amdgcn_sdot8)
    return __builtin_amdgcn_sdot8((int)a, b, c, false);
#else
    int r = c;
#pragma unroll
    for (int i = 0; i < 8; ++i) {
        int av = (int)((a >> (4 * i)) & 0xFu);
        int bv = ((int)(((uint32_t)b) << (28 - 4 * i))) >> 28;
        r += av * bv;
    }
    return r;
#endif
}

__device__ __forceinline__ float rfl_f(float v) {
    return __int_as_float(__builtin_amdgcn_readfirstlane(__float_as_int(v)));
}
__device__ __forceinline__ float recip1(float d) {
    float y0 = __builtin_amdgcn_rcpf(d);
    float e  = fmaf(-d, y0, 1.0f);
    return fmaf(y0, e, y0);
}
// Markstein correctly-rounded division (bit-exact vs __fdiv_rn; validated r12/r13)
__device__ __forceinline__ float mdiv(float n, float d, float y) {
    float q0 = __fmul_rn(n, y);
    float rr = fmaf(-d, q0, n);
    return fmaf(rr, y, q0);
}

__device__ __forceinline__ int wquant(const float* w, float s_w,
                                      int co, int ci, int tap) {
    const int kh = tap / 3, kw = tap % 3;
    float wv = w[((co * CIN + ci) * 3 + kh) * 3 + kw];
    float q  = rintf(__fdiv_rn(wv, s_w));
    q = fminf(fmaxf(q, -7.0f), 7.0f);
    return (int)q;
}

// ---- shared macros ----
#define WPREP(wlds_, weight_, swv_)                                          \
    if (t < 40) {                                                            \
        uint32_t v = 0;                                                      \
        if (t < 32) {                                                        \
            const int co = t >> 2, p = t & 3;                                \
            const int tA = (p == 0) ? 0 : (p == 1) ? 3 : (p == 2) ? 6 : 2;   \
            const int tB = (p == 0) ? 1 : (p == 1) ? 4 : (p == 2) ? 7 : 5;   \
            _Pragma("unroll")                                                \
            for (int ci = 0; ci < CIN; ++ci) {                               \
                v |= ((uint32_t)(wquant(weight_, swv_, co, ci, tA) & 0xF)) << (8 * ci);      \
                v |= ((uint32_t)(wquant(weight_, swv_, co, ci, tB) & 0xF)) << (8 * ci + 4);  \
            }                                                                \
        } else {                                                             \
            const int co = t - 32;                                           \
            _Pragma("unroll")                                                \
            for (int ci = 0; ci < CIN; ++ci)                                 \
                v |= ((uint32_t)(wquant(weight_, swv_, co, ci, 8) & 0xFF)) << (8 * ci);      \
        }                                                                    \
        wlds_[t] = v;                                                        \
    }

#define LOADW_LDS(wlds_)                                                     \
    int w8s[32], w4s[8];                                                     \
    _Pragma("unroll")                                                        \
    for (int i = 0; i < 32; ++i)                                             \
        w8s[i] = __builtin_amdgcn_readfirstlane((int)wlds_[i]);              \
    _Pragma("unroll")                                                        \
    for (int i = 0; i < 8; ++i)                                              \
        w4s[i] = __builtin_amdgcn_readfirstlane((int)wlds_[32 + i]);

#define SWZ()                                                                \
    const int raw = blockIdx.x;                                              \
    const int lin = (raw & 7) * (NBLK / 8) + (raw >> 3);                     \
    const int bx = lin & 1;                                                  \
    const int hy = (lin >> 1) & (GY - 1);                                    \
    const int b  = lin >> 7;                                                 \
    const int w0 = bx * 256 + threadIdx.x;                                   \
    const int h0 = hy * RPB;

#define EXTS(CA, SG, v0, v1, v2)                                             \
    do {                                                                     \
        uint32_t lo_ = ((v0) & 0x0F0F0F0Fu) | (((v1) << 4) & 0xF0F0F0F0u);   \
        uint32_t hi_ = (((v0) >> 4) & 0x0F0F0F0Fu) | ((v1) & 0xF0F0F0F0u);   \
        CA[0] = lo_ & 0x33333333u;                                           \
        CA[1] = (lo_ >> 2) & 0x33333333u;                                    \
        CA[2] = hi_ & 0x33333333u;                                           \
        CA[3] = (hi_ >> 2) & 0x33333333u;                                    \
        SG[0] = (v2)&0x03030303u;                                            \
        SG[1] = ((v2) >> 2) & 0x03030303u;                                   \
        SG[2] = ((v2) >> 4) & 0x03030303u;                                   \
        SG[3] = ((v2) >> 6) & 0x03030303u;                                   \
    } while (0)

#define DOTS(CAa, SGa, CAb, SGb, CAc, SGc, K, INIT, OUTV)                    \
    {                                                                        \
        int a_ = dot4(SGc[K], w4s[co], INIT);                                \
        a_ = dot8(CAa[K], w8s[co * 4 + 0], a_);                              \
        a_ = dot8(CAb[K], w8s[co * 4 + 1], a_);                              \
        a_ = dot8(CAc[K], w8s[co * 4 + 2], a_);                              \
        a_ = dot8(K == 0 ? pc0 : K == 1 ? pc1 : K == 2 ? pc2 : pc3,          \
                  w8s[co * 4 + 3], a_);                                      \
        OUTV = a_;                                                           \
    }

// ============ kernel 1: fused quant + absmax conv ============
__device__ __forceinline__ uint32_t qone(float fv, float s_in, float yin) {
    float q = rintf(mdiv(fv, s_in, yin));
    q = fminf(fmaxf(q, 0.0f), 255.0f);
    return (uint32_t)(int)q;
}

__global__ __launch_bounds__(256, 6) void conv_absmax_fused(
        const float* __restrict__ x, const float* __restrict__ weight,
        const float* __restrict__ s_in_p, const float* __restrict__ s_w_p,
        uint32_t* __restrict__ xq, int* __restrict__ absmax) {
    __shared__ uint32_t wlds[40];
    __shared__ int red[4];
    const int t = threadIdx.x;
    {
        const float s_w = *s_w_p;
        WPREP(wlds, weight, s_w);
    }
    SWZ();
    const float s_in = *s_in_p;
    const float yin  = recip1(s_in);
    __syncthreads();
    LOADW_LDS(wlds);

    const int c = w0;                       // this thread's data column (0..511)
    const size_t plane = (size_t)H_ * W_;
    const float* xb = x + (size_t)b * CIN * plane;
    uint32_t* xqb = xq + (size_t)b * HP * WP;

    // border zeros for pass 2 (redundant same-value writes are benign)
    if (hy == 0)
        for (int i = t; i < WP; i += 256) xqb[i] = 0;
    if (hy == GY - 1)
        for (int i = t; i < WP; i += 256) xqb[(size_t)(HP - 1) * WP + i] = 0;
    if (t == 0) {
        const int col = (bx == 0) ? 0 : (WP - 1);
#pragma unroll
        for (int r = 0; r < RPB; ++r)
            xqb[(size_t)(h0 + 1 + r) * WP + col] = 0;
    }

    float f0, f1, f2, f3;
#define LOADR(d)                                                             \
    do {                                                                     \
        if ((unsigned)(d) < (unsigned)H_) {                                  \
            const float* p_ = xb + (size_t)(d)*W_ + c;                       \
            f0 = p_[0]; f1 = p_[plane]; f2 = p_[2 * plane]; f3 = p_[3 * plane]; \
        } else { f0 = f1 = f2 = f3 = 0.0f; }                                 \
    } while (0)

#define QDIR(d, cc) __extension__({                                         \
    uint32_t v_ = 0;                                                         \
    if ((unsigned)(d) < (unsigned)H_ && (unsigned)(cc) < (unsigned)W_) {     \
        const float* p_ = xb + (size_t)(d)*W_ + (cc);                        \
        v_ = qone(p_[0], s_in, yin) | (qone(p_[plane], s_in, yin) << 8) |    \
             (qone(p_[2 * plane], s_in, yin) << 16) |                        \
             (qone(p_[3 * plane], s_in, yin) << 24);                         \
    }                                                                        \
    v_; })

    // quantize carried floats (row d) -> own word; halo via wave shuffle;
    // wave-edge lanes recompute neighbor column directly from x.
#define QSTEP(d, CA, SG)                                                     \
    do {                                                                     \
        uint32_t M_ = qone(f0, s_in, yin) | (qone(f1, s_in, yin) << 8) |     \
                      (qone(f2, s_in, yin) << 16) | (qone(f3, s_in, yin) << 24); \
        uint32_t L_ = __shfl_up(M_, 1);                                      \
        uint32_t R_ = __shfl_down(M_, 1);                                    \
        if ((t & 63) == 0)  L_ = QDIR((d), c - 1);                           \
        if ((t & 63) == 63) R_ = QDIR((d), c + 1);                           \
        if ((d) >= h0 && (d) <= h0 + RPB - 1)                                \
            xqb[(size_t)((d) + 1) * WP + (c + 1)] = M_;                      \
        EXTS(CA, SG, L_, M_, R_);                                            \
    } while (0)

    uint32_t cA0[4], cA1[4], cA2[4], cA3[4];
    uint32_t sg0[4], sg1[4], sg2[4], sg3[4];

    LOADR(h0 - 1);
    QSTEP(h0 - 1, cA0, sg0);
    LOADR(h0);
    QSTEP(h0, cA1, sg1);
    LOADR(h0 + 1);

    int rMax0 = 0, rMax1 = 0, rMax2 = 0, rMax3 = 0;
    int rMin0 = 0, rMin1 = 0, rMin2 = 0, rMin3 = 0;

#define STEP1F(S, CAa, SGa, CAb, SGb, CAc, SGc)                              \
    do {                                                                     \
        QSTEP(h0 + (S) + 1, CAc, SGc);                                       \
        if ((S) < RPB - 1) LOADR(h0 + (S) + 2);                              \
        const uint32_t pc0 = SGa[0] | (SGb[0] << 4);                         \
        const uint32_t pc1 = SGa[1] | (SGb[1] << 4);                         \
        const uint32_t pc2 = SGa[2] | (SGb[2] << 4);                         \
        const uint32_t pc3 = SGa[3] | (SGb[3] << 4);                         \
        _Pragma("unroll")                                                    \
        for (int co = 0; co < COUT; ++co) {                                  \
            int a0, a1, a2, a3;                                              \
            DOTS(CAa, SGa, CAb, SGb, CAc, SGc, 0, 0, a0);                    \
            DOTS(CAa, SGa, CAb, SGb, CAc, SGc, 1, 0, a1);                    \
            DOTS(CAa, SGa, CAb, SGb, CAc, SGc, 2, 0, a2);                    \
            DOTS(CAa, SGa, CAb, SGb, CAc, SGc, 3, 0, a3);                    \
            rMax0 = max(rMax0, a0); rMin0 = min(rMin0, a0);                  \
            rMax1 = max(rMax1, a1); rMin1 = min(rMin1, a1);                  \
            rMax2 = max(rMax2, a2); rMin2 = min(rMin2, a2);                  \
            rMax3 = max(rMax3, a3); rMin3 = min(rMin3, a3);                  \
        }                                                                    \
    } while (0)

    STEP1F(0, cA0, sg0, cA1, sg1, cA2, sg2);
    STEP1F(1, cA1, sg1, cA2, sg2, cA3, sg3);
    STEP1F(2, cA2, sg2, cA3, sg3, cA0, sg0);
    STEP1F(3, cA3, sg3, cA0, sg0, cA1, sg1);
    STEP1F(4, cA0, sg0, cA1, sg1, cA2, sg2);
    STEP1F(5, cA1, sg1, cA2, sg2, cA3, sg3);
    STEP1F(6, cA2, sg2, cA3, sg3, cA0, sg0);
    STEP1F(7, cA3, sg3, cA0, sg0, cA1, sg1);

    int m = max(max(max(rMax0, -rMin0), max(rMax1, -rMin1)),
                max(max(rMax2, -rMin2), max(rMax3, -rMin3)));
#pragma unroll
    for (int off = 1; off < 64; off <<= 1)
        m = max(m, __shfl_xor(m, off));
    if ((t & 63) == 0) red[t >> 6] = m;
    __syncthreads();
    if (t == 0)
        atomicMax(absmax, max(max(red[0], red[1]), max(red[2], red[3])));
}

// ============ kernel 2: conv + ADC LUT + epilogue (round-12 form) ============
#define RING_INIT()                                                          \
    uint32_t cA0[4], cA1[4], cA2[4], cA3[4];                                 \
    uint32_t sg0[4], sg1[4], sg2[4], sg3[4];                                 \
    {                                                                        \
        uint32_t r0 = base[0], r1 = base[1], r2 = base[2];                   \
        EXTS(cA0, sg0, r0, r1, r2);                                          \
        r0 = base[WP]; r1 = base[WP + 1]; r2 = base[WP + 2];                 \
        EXTS(cA1, sg1, r0, r1, r2);                                          \
    }                                                                        \
    uint32_t n0 = base[2 * WP], n1 = base[2 * WP + 1], n2 = base[2 * WP + 2];

#define PREF(S)                                                              \
    if ((S) < RPB - 1) {                                                     \
        const uint32_t* nr_ = base + (size_t)((S) + 3) * WP;                 \
        n0 = nr_[0]; n1 = nr_[1]; n2 = nr_[2];                               \
    }

#define STEP2(S, CAa, SGa, CAb, SGb, CAc, SGc)                               \
    do {                                                                     \
        EXTS(CAc, SGc, n0, n1, n2);                                          \
        PREF(S);                                                             \
        const uint32_t pc0 = SGa[0] | (SGb[0] << 4);                         \
        const uint32_t pc1 = SGa[1] | (SGb[1] << 4);                         \
        const uint32_t pc2 = SGa[2] | (SGb[2] << 4);                         \
        const uint32_t pc3 = SGa[3] | (SGb[3] << 4);                         \
        int ax[COUT][4];                                                     \
        _Pragma("unroll")                                                    \
        for (int co = 0; co < COUT; ++co) {                                  \
            DOTS(CAa, SGa, CAb, SGb, CAc, SGc, 0, PMAX, ax[co][0]);          \
            DOTS(CAa, SGa, CAb, SGb, CAc, SGc, 1, PMAX, ax[co][1]);          \
            DOTS(CAa, SGa, CAb, SGb, CAc, SGc, 2, PMAX, ax[co][2]);          \
            DOTS(CAa, SGa, CAb, SGb, CAc, SGc, 3, PMAX, ax[co][3]);          \
        }                                                                    \
        float tv[COUT][4];                                                   \
        _Pragma("unroll")                                                    \
        for (int co = 0; co < COUT; ++co) {                                  \
            tv[co][0] = T0[ax[co][0]];                                       \
            tv[co][1] = T4[ax[co][1]];                                       \
            tv[co][2] = T0[ax[co][2]];                                       \
            tv[co][3] = T4[ax[co][3]];                                       \
        }                                                                    \
        float* orow = out + ((size_t)b * COUT * H_ + (size_t)(h0 + (S))) * W_ + w0; \
        _Pragma("unroll")                                                    \
        for (int co = 0; co < COUT; ++co) {                                  \
            float of = __fadd_rn(tv[co][0], tv[co][1]);                      \
            of = __fadd_rn(of, __fmul_rn(tv[co][2], 16.0f));                 \
            of = __fadd_rn(of, __fmul_rn(tv[co][3], 16.0f));                 \
            float o_ = __fadd_rn(__fmul_rn(of, scale), br[co]);              \
            float q0 = __fmul_rn(o_, y1);                                    \
            float rr = fmaf(-s_out, q0, o_);                                 \
            float qd = fmaf(rr, y1, q0);                                     \
            float q_ = rintf(qd);                                            \
            q_ = fminf(fmaxf(q_, -127.0f), 127.0f);                          \
            orow[(size_t)co * plane] = __fmul_rn(q_, s_out);                 \
        }                                                                    \
    } while (0)

__global__ __launch_bounds__(256) void conv_out(
        const uint32_t* __restrict__ xq, const float* __restrict__ weight,
        const float* __restrict__ bias, const float* __restrict__ sp_in,
        const float* __restrict__ sp_w, const float* __restrict__ sp_out,
        const int* __restrict__ absmax, float* __restrict__ out) {
    __shared__ float T0[TBL];
    __shared__ float T4[TBL];
    __shared__ uint32_t wlds[40];
    const int t = threadIdx.x;
    {
        const float s_w = *sp_w;
        WPREP(wlds, weight, s_w);
    }
    const float pabs = fmaxf((float)(*absmax), 1e-6f);
    const float c63  = 1.0f / 63.0f;
    float g = rintf(__fdiv_rn(127.0f, __fmul_rn(pabs, c63)));
    g = fminf(fmaxf(g, 1.0f), 255.0f);
    const float step = __fdiv_rn(1.0f, __fmul_rn(g, c63));
    for (int i = t; i < TBL; i += 256) {
        float p = (float)(i - PMAX);
        float r = rintf(__fdiv_rn(p, step));
        r = fminf(fmaxf(r, -127.0f), 127.0f);
        float v = __fmul_rn(r, step);
        T0[i] = v;
        T4[i] = 4.0f * v;          // exact
    }
    const float scale = __fmul_rn(rfl_f(*sp_in), rfl_f(*sp_w));
    const float s_out = rfl_f(*sp_out);
    const float y1    = recip1(s_out);
    float br[COUT];
#pragma unroll
    for (int co = 0; co < COUT; ++co) br[co] = rfl_f(bias[co]);
    __syncthreads();
    LOADW_LDS(wlds);

    SWZ();
    const uint32_t* base = xq + ((size_t)b * HP + h0) * WP + w0;
    const size_t plane = (size_t)H_ * W_;
    RING_INIT();
    STEP2(0, cA0, sg0, cA1, sg1, cA2, sg2);
    STEP2(1, cA1, sg1, cA2, sg2, cA3, sg3);
    STEP2(2, cA2, sg2, cA3, sg3, cA0, sg0);
    STEP2(3, cA3, sg3, cA0, sg0, cA1, sg1);
    STEP2(4, cA0, sg0, cA1, sg1, cA2, sg2);
    STEP2(5, cA1, sg1, cA2, sg2, cA3, sg3);
    STEP2(6, cA2, sg2, cA3, sg3, cA0, sg0);
    STEP2(7, cA3, sg3, cA0, sg0, cA1, sg1);
}

extern "C" void kernel_launch(void* const* d_in, const int* in_sizes, int n_in,
                              void* d_out, int out_size, void* d_ws, size_t ws_size,
                              hipStream_t stream) {
    const float* x      = (const float*)d_in[0];
    const float* weight = (const float*)d_in[1];
    const float* bias   = (const float*)d_in[2];
    const float* s_in   = (const float*)d_in[3];
    const float* s_w    = (const float*)d_in[4];
    const float* s_out  = (const float*)d_in[5];
    float* out = (float*)d_out;

    int*      absmax = (int*)d_ws;
    uint32_t* xq     = (uint32_t*)((char*)d_ws + 1024);

    hipMemsetAsync(absmax, 0, sizeof(int), stream);

    conv_absmax_fused<<<dim3(NBLK), dim3(256), 0, stream>>>(
        x, weight, s_in, s_w, xq, absmax);

    conv_out<<<dim3(NBLK), dim3(256), 0, stream>>>(
        xq, weight, bias, s_in, s_w, s_out, absmax, out);
}

// Round 15
// 92.782 us; speedup vs baseline: 1.1986x; 1.1280x over previous
//
#include <hip/hip_runtime.h>
#include <stdint.h>

#define B_   16
#define CIN  4
#define COUT 8
#define H_   512
#define W_   512
#define HP   (H_ + 2)
#define WP   (W_ + 2)
#define PMAX 756
#define TBL  (2 * PMAX + 1)
#define RPB  8                    // output rows per block
#define GY   (H_ / RPB)           // 64
#define NBLK (2 * GY * B_)        // 2048 blocks
#define NQ   (B_ * HP)            // 8224 quant blocks (div by 8)

__device__ __forceinline__ int dot4(uint32_t a, int b, int c) {
#if __has_builtin(__builtin_amdgcn_sdot4)
    return __builtin_amdgcn_sdot4((int)a, b, c, false);
#else
    int r = c;
#pragma unroll
    for (int i = 0; i < 4; ++i) {
        int av = (int)((a >> (8 * i)) & 0xFFu);
        int bv = ((int)(((uint32_t)b) << (24 - 8 * i))) >> 24;
        r += av * bv;
    }
    return r;
#endif
}

__device__ __forceinline__ int dot8(uint32_t a, int b, int c) {
#if __has_builtin(__builtin_amdgcn_sdot8)
    return __builtin_amdgcn_sdot8((int)a, b, c, false);
#else
    int r = c;
#pragma unroll
    for (int i = 0; i < 8; ++i) {
        int av = (int)((a >> (4 * i)) & 0xFu);
        int bv = ((int)(((uint32_t)b) << (28 - 4 * i))) >> 28;
        r += av * bv;
    }
    return r;
#endif
}

__device__ __forceinline__ float rfl_f(float v) {
    return __int_as_float(__builtin_amdgcn_readfirstlane(__float_as_int(v)));
}
__device__ __forceinline__ float recip1(float d) {
    float y0 = __builtin_amdgcn_rcpf(d);
    float e  = fmaf(-d, y0, 1.0f);
    return fmaf(y0, e, y0);
}
// Markstein correctly-rounded division (bit-exact vs __fdiv_rn; validated r12/r13)
__device__ __forceinline__ float mdiv(float n, float d, float y) {
    float q0 = __fmul_rn(n, y);
    float rr = fmaf(-d, q0, n);
    return fmaf(rr, y, q0);
}

__device__ __forceinline__ int wquant(const float* w, float s_w,
                                      int co, int ci, int tap) {
    const int kh = tap / 3, kw = tap % 3;
    float wv = w[((co * CIN + ci) * 3 + kh) * 3 + kw];
    float q  = rintf(__fdiv_rn(wv, s_w));
    q = fminf(fmaxf(q, -7.0f), 7.0f);
    return (int)q;
}

// ---------------- quant + weight pack ----------------
__global__ __launch_bounds__(128) void quant_pack_kernel(
        const float* __restrict__ x, const float* __restrict__ weight,
        const float* __restrict__ s_in_p, const float* __restrict__ s_w_p,
        uint32_t* __restrict__ xq, uint32_t* __restrict__ wq8) {
    const int raw = blockIdx.x;
    const int lin = (raw & 7) * (NQ / 8) + (raw >> 3);
    const int b = lin / HP, hp = lin % HP;
    const int t = threadIdx.x;
    if (raw == 0) {
        const float s_w = *s_w_p;
        if (t < 32) {                        // nibble pairs (0,1)(3,4)(6,7)(2,5)
            const int co = t >> 2, p = t & 3;
            const int tA = (p == 0) ? 0 : (p == 1) ? 3 : (p == 2) ? 6 : 2;
            const int tB = (p == 0) ? 1 : (p == 1) ? 4 : (p == 2) ? 7 : 5;
            uint32_t v = 0;
#pragma unroll
            for (int ci = 0; ci < CIN; ++ci) {
                v |= ((uint32_t)(wquant(weight, s_w, co, ci, tA) & 0xF)) << (8 * ci);
                v |= ((uint32_t)(wquant(weight, s_w, co, ci, tB) & 0xF)) << (8 * ci + 4);
            }
            wq8[t] = v;
        } else if (t < 40) {                 // tap-8 bytes
            const int co = t - 32;
            uint32_t v = 0;
#pragma unroll
            for (int ci = 0; ci < CIN; ++ci)
                v |= ((uint32_t)(wquant(weight, s_w, co, ci, 8) & 0xFF)) << (8 * ci);
            wq8[32 + co] = v;
        }
    }
    uint32_t* dst = xq + ((size_t)b * HP + hp) * WP;
    if (hp == 0 || hp == HP - 1) {
        for (int i = t; i < WP; i += 128) dst[i] = 0;
        return;
    }
    const float s_in = *s_in_p;
    const float yin  = recip1(s_in);
    const int h = hp - 1;
    const size_t plane = (size_t)H_ * W_;
    const float* xr = x + ((size_t)b * CIN) * plane + (size_t)h * W_ + 4 * t;
    float4 v0 = *(const float4*)(xr);
    float4 v1 = *(const float4*)(xr + plane);
    float4 v2 = *(const float4*)(xr + 2 * plane);
    float4 v3 = *(const float4*)(xr + 3 * plane);
    uint32_t o0 = 0, o1 = 0, o2 = 0, o3 = 0;
#define QP(f, ci, oj)                                                  \
    { float q = rintf(mdiv((f), s_in, yin));                           \
      q = fminf(fmaxf(q, 0.0f), 255.0f);                               \
      oj |= ((uint32_t)(int)q) << (8 * (ci)); }
    QP(v0.x, 0, o0) QP(v0.y, 0, o1) QP(v0.z, 0, o2) QP(v0.w, 0, o3)
    QP(v1.x, 1, o0) QP(v1.y, 1, o1) QP(v1.z, 1, o2) QP(v1.w, 1, o3)
    QP(v2.x, 2, o0) QP(v2.y, 2, o1) QP(v2.z, 2, o2) QP(v2.w, 2, o3)
    QP(v3.x, 3, o0) QP(v3.y, 3, o1) QP(v3.z, 3, o2) QP(v3.w, 3, o3)
#undef QP
    uint32_t* d = dst + 1 + 4 * t;
    d[0] = o0; d[1] = o1; d[2] = o2; d[3] = o3;
    if (t == 0) dst[0] = 0;
    if (t == 127) dst[WP - 1] = 0;
}

// ---------------- shared conv machinery ----------------
// Weights in plain VGPR arrays. NO readfirstlane: SGPR operands on v_dot
// were never folded (r2 null + persistent 2-3x instr bloat at VGPR<=36),
// costing a v_mov per dot. VGPR budget opened via __launch_bounds__(256,2).
#define LOADW()                                                              \
    int w8s[32], w4s[8];                                                     \
    {                                                                        \
        const int4* q4 = (const int4*)wq8;                                   \
        _Pragma("unroll")                                                    \
        for (int i = 0; i < 8; ++i) {                                        \
            int4 w4i = q4[i];                                                \
            w8s[4 * i + 0] = w4i.x;                                          \
            w8s[4 * i + 1] = w4i.y;                                          \
            w8s[4 * i + 2] = w4i.z;                                          \
            w8s[4 * i + 3] = w4i.w;                                          \
        }                                                                    \
        int4 a0 = q4[8], a1 = q4[9];                                         \
        w4s[0] = a0.x; w4s[1] = a0.y; w4s[2] = a0.z; w4s[3] = a0.w;          \
        w4s[4] = a1.x; w4s[5] = a1.y; w4s[6] = a1.z; w4s[7] = a1.w;          \
    }

#define SWZ()                                                                \
    const int raw = blockIdx.x;                                              \
    const int lin = (raw & 7) * (NBLK / 8) + (raw >> 3);                     \
    const int bx = lin & 1;                                                  \
    const int hy = (lin >> 1) & (GY - 1);                                    \
    const int b  = lin >> 7;                                                 \
    const int w0 = bx * 256 + threadIdx.x;                                   \
    const int h0 = hy * RPB;

#define EXTS(CA, SG, v0, v1, v2)                                             \
    do {                                                                     \
        uint32_t lo_ = ((v0) & 0x0F0F0F0Fu) | (((v1) << 4) & 0xF0F0F0F0u);   \
        uint32_t hi_ = (((v0) >> 4) & 0x0F0F0F0Fu) | ((v1) & 0xF0F0F0F0u);   \
        CA[0] = lo_ & 0x33333333u;                                           \
        CA[1] = (lo_ >> 2) & 0x33333333u;                                    \
        CA[2] = hi_ & 0x33333333u;                                           \
        CA[3] = (hi_ >> 2) & 0x33333333u;                                    \
        SG[0] = (v2)&0x03030303u;                                            \
        SG[1] = ((v2) >> 2) & 0x03030303u;                                   \
        SG[2] = ((v2) >> 4) & 0x03030303u;                                   \
        SG[3] = ((v2) >> 6) & 0x03030303u;                                   \
    } while (0)

#define RING_INIT()                                                          \
    uint32_t cA0[4], cA1[4], cA2[4], cA3[4];                                 \
    uint32_t sg0[4], sg1[4], sg2[4], sg3[4];                                 \
    {                                                                        \
        uint32_t r0 = base[0], r1 = base[1], r2 = base[2];                   \
        EXTS(cA0, sg0, r0, r1, r2);                                          \
        r0 = base[WP]; r1 = base[WP + 1]; r2 = base[WP + 2];                 \
        EXTS(cA1, sg1, r0, r1, r2);                                          \
    }                                                                        \
    uint32_t n0 = base[2 * WP], n1 = base[2 * WP + 1], n2 = base[2 * WP + 2];

#define PREF(S)                                                              \
    if ((S) < RPB - 1) {                                                     \
        const uint32_t* nr_ = base + (size_t)((S) + 3) * WP;                 \
        n0 = nr_[0]; n1 = nr_[1]; n2 = nr_[2];                               \
    }

#define DOTS(CAa, SGa, CAb, SGb, CAc, SGc, K, INIT, OUTV)                    \
    {                                                                        \
        int a_ = dot4(SGc[K], w4s[co], INIT);                                \
        a_ = dot8(CAa[K], w8s[co * 4 + 0], a_);                              \
        a_ = dot8(CAb[K], w8s[co * 4 + 1], a_);                              \
        a_ = dot8(CAc[K], w8s[co * 4 + 2], a_);                              \
        a_ = dot8(K == 0 ? pc0 : K == 1 ? pc1 : K == 2 ? pc2 : pc3,          \
                  w8s[co * 4 + 3], a_);                                      \
        OUTV = a_;                                                           \
    }

// ---------------- pass 1: absmax ----------------
#define STEP1(S, CAa, SGa, CAb, SGb, CAc, SGc)                               \
    do {                                                                     \
        EXTS(CAc, SGc, n0, n1, n2);                                          \
        PREF(S);                                                             \
        const uint32_t pc0 = SGa[0] | (SGb[0] << 4);                         \
        const uint32_t pc1 = SGa[1] | (SGb[1] << 4);                         \
        const uint32_t pc2 = SGa[2] | (SGb[2] << 4);                         \
        const uint32_t pc3 = SGa[3] | (SGb[3] << 4);                         \
        _Pragma("unroll")                                                    \
        for (int co = 0; co < COUT; ++co) {                                  \
            int a0, a1, a2, a3;                                              \
            DOTS(CAa, SGa, CAb, SGb, CAc, SGc, 0, 0, a0);                    \
            DOTS(CAa, SGa, CAb, SGb, CAc, SGc, 1, 0, a1);                    \
            DOTS(CAa, SGa, CAb, SGb, CAc, SGc, 2, 0, a2);                    \
            DOTS(CAa, SGa, CAb, SGb, CAc, SGc, 3, 0, a3);                    \
            rMax0 = max(rMax0, a0); rMin0 = min(rMin0, a0);                  \
            rMax1 = max(rMax1, a1); rMin1 = min(rMin1, a1);                  \
            rMax2 = max(rMax2, a2); rMin2 = min(rMin2, a2);                  \
            rMax3 = max(rMax3, a3); rMin3 = min(rMin3, a3);                  \
        }                                                                    \
    } while (0)

__global__ __launch_bounds__(256, 2) void conv_absmax(
        const uint32_t* __restrict__ xq, const uint32_t* __restrict__ wq8,
        int* __restrict__ blkmax) {
    __shared__ int red[4];
    LOADW();
    SWZ();
    const uint32_t* base = xq + ((size_t)b * HP + h0) * WP + w0;
    RING_INIT();
    int rMax0 = 0, rMax1 = 0, rMax2 = 0, rMax3 = 0;
    int rMin0 = 0, rMin1 = 0, rMin2 = 0, rMin3 = 0;
    STEP1(0, cA0, sg0, cA1, sg1, cA2, sg2);
    STEP1(1, cA1, sg1, cA2, sg2, cA3, sg3);
    STEP1(2, cA2, sg2, cA3, sg3, cA0, sg0);
    STEP1(3, cA3, sg3, cA0, sg0, cA1, sg1);
    STEP1(4, cA0, sg0, cA1, sg1, cA2, sg2);
    STEP1(5, cA1, sg1, cA2, sg2, cA3, sg3);
    STEP1(6, cA2, sg2, cA3, sg3, cA0, sg0);
    STEP1(7, cA3, sg3, cA0, sg0, cA1, sg1);
    int m = max(max(max(rMax0, -rMin0), max(rMax1, -rMin1)),
                max(max(rMax2, -rMin2), max(rMax3, -rMin3)));
#pragma unroll
    for (int off = 1; off < 64; off <<= 1)
        m = max(m, __shfl_xor(m, off));
    if ((threadIdx.x & 63) == 0) red[threadIdx.x >> 6] = m;
    __syncthreads();
    if (threadIdx.x == 0)
        blkmax[raw] = max(max(red[0], red[1]), max(red[2], red[3]));
}

__global__ __launch_bounds__(256) void reduce_absmax(
        const int* __restrict__ blkmax, int* __restrict__ absmax) {
    __shared__ int red[4];
    const int t = threadIdx.x;
    int m = 0;
#pragma unroll
    for (int i = 0; i < NBLK / 256; ++i) m = max(m, blkmax[t + 256 * i]);
#pragma unroll
    for (int off = 1; off < 64; off <<= 1)
        m = max(m, __shfl_xor(m, off));
    if ((t & 63) == 0) red[t >> 6] = m;
    __syncthreads();
    if (t == 0)
        *absmax = max(max(red[0], red[1]), max(red[2], red[3]));
}

// ---------------- pass 2: LUT + dieted epilogue (r12 form) ----------------
#define STEP2(S, CAa, SGa, CAb, SGb, CAc, SGc)                               \
    do {                                                                     \
        EXTS(CAc, SGc, n0, n1, n2);                                          \
        PREF(S);                                                             \
        const uint32_t pc0 = SGa[0] | (SGb[0] << 4);                         \
        const uint32_t pc1 = SGa[1] | (SGb[1] << 4);                         \
        const uint32_t pc2 = SGa[2] | (SGb[2] << 4);                         \
        const uint32_t pc3 = SGa[3] | (SGb[3] << 4);                         \
        int ax[COUT][4];                                                     \
        _Pragma("unroll")                                                    \
        for (int co = 0; co < COUT; ++co) {                                  \
            DOTS(CAa, SGa, CAb, SGb, CAc, SGc, 0, PMAX, ax[co][0]);          \
            DOTS(CAa, SGa, CAb, SGb, CAc, SGc, 1, PMAX, ax[co][1]);          \
            DOTS(CAa, SGa, CAb, SGb, CAc, SGc, 2, PMAX, ax[co][2]);          \
            DOTS(CAa, SGa, CAb, SGb, CAc, SGc, 3, PMAX, ax[co][3]);          \
        }                                                                    \
        float tv[COUT][4];                                                   \
        _Pragma("unroll")                                                    \
        for (int co = 0; co < COUT; ++co) {                                  \
            tv[co][0] = T0[ax[co][0]];                                       \
            tv[co][1] = T4[ax[co][1]];                                       \
            tv[co][2] = T0[ax[co][2]];                                       \
            tv[co][3] = T4[ax[co][3]];                                       \
        }                                                                    \
        float* orow = out + ((size_t)b * COUT * H_ + (size_t)(h0 + (S))) * W_ + w0; \
        _Pragma("unroll")                                                    \
        for (int co = 0; co < COUT; ++co) {                                  \
            float of = __fadd_rn(tv[co][0], tv[co][1]);                      \
            of = __fadd_rn(of, __fmul_rn(tv[co][2], 16.0f));                 \
            of = __fadd_rn(of, __fmul_rn(tv[co][3], 16.0f));                 \
            float o_ = __fadd_rn(__fmul_rn(of, scale), br[co]);              \
            float q0 = __fmul_rn(o_, y1);                                    \
            float rr = fmaf(-s_out, q0, o_);                                 \
            float qd = fmaf(rr, y1, q0);                                     \
            float q_ = rintf(qd);                                            \
            q_ = fminf(fmaxf(q_, -127.0f), 127.0f);                          \
            orow[(size_t)co * plane] = __fmul_rn(q_, s_out);                 \
        }                                                                    \
    } while (0)

__global__ __launch_bounds__(256, 2) void conv_out(
        const uint32_t* __restrict__ xq, const uint32_t* __restrict__ wq8,
        const float* __restrict__ bias, const float* __restrict__ sp_in,
        const float* __restrict__ sp_w, const float* __restrict__ sp_out,
        const int* __restrict__ absmax, float* __restrict__ out) {
    __shared__ float T0[TBL];
    __shared__ float T4[TBL];
    LOADW();
    const float pabs = fmaxf((float)(*absmax), 1e-6f);
    const float c63  = 1.0f / 63.0f;
    float g = rintf(__fdiv_rn(127.0f, __fmul_rn(pabs, c63)));
    g = fminf(fmaxf(g, 1.0f), 255.0f);
    const float step = __fdiv_rn(1.0f, __fmul_rn(g, c63));
    for (int i = threadIdx.x; i < TBL; i += 256) {
        float p = (float)(i - PMAX);
        float r = rintf(__fdiv_rn(p, step));
        r = fminf(fmaxf(r, -127.0f), 127.0f);
        float v = __fmul_rn(r, step);
        T0[i] = v;
        T4[i] = 4.0f * v;          // exact
    }
    const float scale = __fmul_rn(rfl_f(*sp_in), rfl_f(*sp_w));
    const float s_out = rfl_f(*sp_out);
    const float y1    = recip1(s_out);
    float br[COUT];
#pragma unroll
    for (int co = 0; co < COUT; ++co) br[co] = rfl_f(bias[co]);
    __syncthreads();

    SWZ();
    const uint32_t* base = xq + ((size_t)b * HP + h0) * WP + w0;
    const size_t plane = (size_t)H_ * W_;
    RING_INIT();
    STEP2(0, cA0, sg0, cA1, sg1, cA2, sg2);
    STEP2(1, cA1, sg1, cA2, sg2, cA3, sg3);
    STEP2(2, cA2, sg2, cA3, sg3, cA0, sg0);
    STEP2(3, cA3, sg3, cA0, sg0, cA1, sg1);
    STEP2(4, cA0, sg0, cA1, sg1, cA2, sg2);
    STEP2(5, cA1, sg1, cA2, sg2, cA3, sg3);
    STEP2(6, cA2, sg2, cA3, sg3, cA0, sg0);
    STEP2(7, cA3, sg3, cA0, sg0, cA1, sg1);
}

extern "C" void kernel_launch(void* const* d_in, const int* in_sizes, int n_in,
                              void* d_out, int out_size, void* d_ws, size_t ws_size,
                              hipStream_t stream) {
    const float* x      = (const float*)d_in[0];
    const float* weight = (const float*)d_in[1];
    const float* bias   = (const float*)d_in[2];
    const float* s_in   = (const float*)d_in[3];
    const float* s_w    = (const float*)d_in[4];
    const float* s_out  = (const float*)d_in[5];
    float* out = (float*)d_out;

    int*      absmax = (int*)d_ws;
    uint32_t* wq8    = (uint32_t*)((char*)d_ws + 256);    // 40 u32
    int*      blkmax = (int*)((char*)d_ws + 1024);        // 2048 ints
    uint32_t* xq     = (uint32_t*)((char*)d_ws + 16384);

    quant_pack_kernel<<<dim3(NQ), dim3(128), 0, stream>>>(
        x, weight, s_in, s_w, xq, wq8);

    conv_absmax<<<dim3(NBLK), dim3(256), 0, stream>>>(xq, wq8, blkmax);

    reduce_absmax<<<dim3(1), dim3(256), 0, stream>>>(blkmax, absmax);

    conv_out<<<dim3(NBLK), dim3(256), 0, stream>>>(
        xq, wq8, bias, s_in, s_w, s_out, absmax, out);
}